// Round 14
// baseline (235.235 us; speedup 1.0000x reference)
//
#include <hip/hip_runtime.h>
#include <cstdint>
#include <cstddef>

// Problem constants
#define S_LEN  2048
#define NHEAD  16
#define HDIM   64
#define KD     1024   // D_IN == D_OUT
#define BSROWS 8192   // B * S

typedef __attribute__((ext_vector_type(4))) float          floatx4;
typedef __attribute__((ext_vector_type(8))) __bf16         bf16x8;
typedef __attribute__((ext_vector_type(8))) unsigned short ushort8v;
typedef __attribute__((ext_vector_type(4))) unsigned short ushort4v;
typedef __attribute__((ext_vector_type(4))) float          float4v;

// fp32 -> bf16 round-to-nearest-even on the bit pattern (inputs are finite)
__device__ __forceinline__ unsigned short f2bf(float f) {
  unsigned int u = __float_as_uint(f);
  u += 0x7fffu + ((u >> 16) & 1u);
  return (unsigned short)(u >> 16);
}

// fast exp2 (single v_exp_f32)
#if __has_builtin(__builtin_amdgcn_exp2f)
#define EXP2F(x) __builtin_amdgcn_exp2f(x)
#else
#define EXP2F(x) exp2f(x)
#endif

// pack two fp32 into packed bf16 (truncation; bias cancels in O/l)
__device__ __forceinline__ unsigned int pack2bf(float a, float b) {
#if __has_builtin(__builtin_amdgcn_perm)
  return __builtin_amdgcn_perm(__float_as_uint(b), __float_as_uint(a), 0x07060302);
#else
  return (__float_as_uint(a) >> 16) | (__float_as_uint(b) & 0xffff0000u);
#endif
}

// async global->LDS, 16B per lane; LDS dest is wave-uniform base + lane*16
__device__ __forceinline__ void async_cp16(const void* gsrc, void* ldst) {
  __builtin_amdgcn_global_load_lds(
      (__attribute__((address_space(1))) void*)gsrc,
      (__attribute__((address_space(3))) void*)ldst,
      16, 0, 0);
}

// ---------------------------------------------------------------------------
// Kernel 1: fp32 -> bf16 conversion of x, W_q|W_k|W_v (concat), W_o
// ---------------------------------------------------------------------------
#define XN4 2097152   // B*S*D_IN / 4
#define WN4 262144    // 1024*1024 / 4

__global__ __launch_bounds__(256) void cvt_kernel(
    const float* __restrict__ x,  const float* __restrict__ wq,
    const float* __restrict__ wk, const float* __restrict__ wv,
    const float* __restrict__ wo,
    unsigned short* __restrict__ xb, unsigned short* __restrict__ wqkvb,
    unsigned short* __restrict__ wob)
{
  const int i = blockIdx.x * 256 + threadIdx.x;
  const float* src; unsigned short* dst; int off;
  if (i < XN4) { src = x; dst = xb; off = i; }
  else {
    const int j = i - XN4;
    if (j < WN4)          { src = wq; dst = wqkvb;           off = j; }
    else if (j < 2*WN4)   { src = wk; dst = wqkvb + 4*WN4;   off = j - WN4; }
    else if (j < 3*WN4)   { src = wv; dst = wqkvb + 8*WN4;   off = j - 2*WN4; }
    else                  { src = wo; dst = wob;             off = j - 3*WN4; }
  }
  const float4v v = ((const float4v*)src)[off];
  ushort4v o;
  o.x = f2bf(v.x); o.y = f2bf(v.y); o.z = f2bf(v.z); o.w = f2bf(v.w);
  ((ushort4v*)dst)[off] = o;
}

// ---------------------------------------------------------------------------
// R15 kloop12 (HW-VERIFIED: gemm_qkv12 + gemm_out12 both passed):
// 128x256 counted-vmcnt K-loop. 8 waves = 2 row-bands(64) x 4 col-bands(64);
// acc 4x4 frags. LDS = 2 buf x (A[128][64] + B[256][64]) = 96 KiB.
// K = 16 tiles x 2 phases: p0 = A frags + B nh0 (16 MFMA), p1 = B nh1.
// Stage halves/tile: hA, hB0 at p0(t); hB1 at p1(t) (dbuf, no WAR).
// ONE vmcnt(4) per tile at p0 (never 0 in steady state); t=15 vmcnt(0).
// XOR source swizzle + linear LDS dest; setprio around MFMA clusters.
// ---------------------------------------------------------------------------
__device__ __forceinline__ void stage_h12(
    const int h, const int tk,
    const unsigned short* __restrict__ gAs,
    const unsigned short* __restrict__ gBs,
    unsigned short* smem, const int wave)
{
  const int bufo = (tk & 1) * 24576;
  const unsigned short* g;
  unsigned short* l;
  if (h == 0)      { g = gAs + tk * 64;                      l = smem + bufo + wave * 512; }
  else if (h == 1) { g = gBs + tk * 64;                      l = smem + bufo + 8192  + wave * 512; }
  else             { g = gBs + (size_t)128 * KD + tk * 64;   l = smem + bufo + 16384 + wave * 512; }
  async_cp16(g,                   l);
  async_cp16(g + (size_t)64 * KD, l + 4096);
}

template<bool SWAP>
__device__ __forceinline__ void kloop12(
    const unsigned short* __restrict__ gAs,
    const unsigned short* __restrict__ gBs,
    unsigned short* smem, floatx4 (&acc)[4][4],
    const int wave, const int quad, const int l15)
{
  const int ar_base = (wave >> 2) * 64 + l15;   // 2 row-bands x 64 (BM=128)
  const int bc_base = (wave & 3) * 64 + l15;    // 4 col-bands x 64 (BN=256)
  const int sw0 = ((quad)     ^ (l15 & 7)) * 8; // chunk swizzle, ks=0
  const int sw1 = ((4 + quad) ^ (l15 & 7)) * 8; // chunk swizzle, ks=1

  bf16x8 af[4][2];     // A frags: loaded at p0, held across the tile
  bf16x8 bfr[2][2];    // B frags of the current nh

  // prologue: all three halves of tile 0
  stage_h12(0, 0, gAs, gBs, smem, wave);
  stage_h12(1, 0, gAs, gBs, smem, wave);
  stage_h12(2, 0, gAs, gBs, smem, wave);

#define MFMAQ12(nh)                                                            \
  __builtin_amdgcn_s_setprio(1);                                               \
  _Pragma("unroll") for (int mt = 0; mt < 4; ++mt)                             \
    _Pragma("unroll") for (int nt = 0; nt < 2; ++nt)                           \
      _Pragma("unroll") for (int ks = 0; ks < 2; ++ks) {                       \
        if (SWAP)                                                              \
          acc[mt][(nh)*2+nt] = __builtin_amdgcn_mfma_f32_16x16x32_bf16(        \
              bfr[nt][ks], af[mt][ks], acc[mt][(nh)*2+nt], 0, 0, 0);           \
        else                                                                   \
          acc[mt][(nh)*2+nt] = __builtin_amdgcn_mfma_f32_16x16x32_bf16(        \
              af[mt][ks], bfr[nt][ks], acc[mt][(nh)*2+nt], 0, 0, 0);           \
      }                                                                        \
  __builtin_amdgcn_s_setprio(0);

#pragma unroll 2
  for (int t = 0; t < 16; ++t) {
    const unsigned short* As = smem + (t & 1) * 24576;
    const unsigned short* Bs = As + 8192;

    // ---- p0: nh = 0
    asm volatile("s_barrier" ::: "memory");       // close prev phase
    if (t + 1 < 16) {
      stage_h12(0, t + 1, gAs, gBs, smem, wave);  // hA(t+1)
      stage_h12(1, t + 1, gAs, gBs, smem, wave);  // hB0(t+1)
    }
    if (t < 15) asm volatile("s_waitcnt vmcnt(4)\n\ts_barrier" ::: "memory");
    else        asm volatile("s_waitcnt vmcnt(0)\n\ts_barrier" ::: "memory");
#pragma unroll
    for (int mt = 0; mt < 4; ++mt) {
      const unsigned short* ar = &As[(ar_base + mt * 16) * 64];
      af[mt][0] = *(const bf16x8*)(ar + sw0);
      af[mt][1] = *(const bf16x8*)(ar + sw1);
    }
#pragma unroll
    for (int nt = 0; nt < 2; ++nt) {
      const unsigned short* br = &Bs[(bc_base + nt * 16) * 64];
      bfr[nt][0] = *(const bf16x8*)(br + sw0);
      bfr[nt][1] = *(const bf16x8*)(br + sw1);
    }
    MFMAQ12(0)

    // ---- p1: nh = 1
    asm volatile("s_barrier" ::: "memory");
    if (t + 1 < 16) stage_h12(2, t + 1, gAs, gBs, smem, wave);  // hB1(t+1)
#pragma unroll
    for (int nt = 0; nt < 2; ++nt) {
      const unsigned short* br = &Bs[(bc_base + 32 + nt * 16) * 64];
      bfr[nt][0] = *(const bf16x8*)(br + sw0);
      bfr[nt][1] = *(const bf16x8*)(br + sw1);
    }
    MFMAQ12(1)
  }
#undef MFMAQ12
}

// fragment coords (SWAP, n-major):  m = (w>>2)*64+mt*16+l15,
//                                   n = (w&3)*64+(jn>>1)*32+(jn&1)*16+quad*4+r
// (no-SWAP, m-major): m gets quad*4+r, n gets l15.
__global__ __launch_bounds__(512, 2) void gemm_qkv12(
    const unsigned short* __restrict__ A,
    const unsigned short* __restrict__ Bw,
    unsigned short* __restrict__ Qo,
    unsigned short* __restrict__ Ko,
    unsigned short* __restrict__ Vto)
{
  __shared__ unsigned short smem[49152];   // 96 KiB
  const int tid  = threadIdx.x;
  const int wave = tid >> 6, lane = tid & 63;
  const int quad = lane >> 4, l15 = lane & 15;

  // XCD swizzle (768 = 8 x 96, bijective); m-outer within XCD: 8 A-panels
  // (2 MB) L2-resident per XCD.
  const int bid = (int)blockIdx.x;
  const int tau = (bid & 7) * 96 + (bid >> 3);
  const int m0 = (tau / 12) * 128, n0 = (tau % 12) * 256;

  const int strow = tid >> 3;                       // 0..63
  const int stxc  = (tid & 7) ^ (strow & 7);        // XOR-swizzled source chunk
  const unsigned short* gAs = A  + (size_t)(m0 + strow) * KD + stxc * 8;
  const unsigned short* gBs = Bw + (size_t)(n0 + strow) * KD + stxc * 8;

  const floatx4 fzero = {0.f, 0.f, 0.f, 0.f};
  floatx4 acc[4][4];
#pragma unroll
  for (int i = 0; i < 4; i++)
#pragma unroll
    for (int j = 0; j < 4; j++) acc[i][j] = fzero;

  const int which = n0 >> 10;                       // 0:Q 1:K 2:V
  if (which < 2) kloop12<true >(gAs, gBs, smem, acc, wave, quad, l15);
  else           kloop12<false>(gAs, gBs, smem, acc, wave, quad, l15);

  const int h0 = (n0 & 1023) >> 6;                  // first of 4 heads
  const int b = m0 >> 11, sl = m0 & 2047;
  __syncthreads();                                  // staging dead -> reuse LDS

  if (which < 2) {
    unsigned short* dst = which ? Ko : Qo;
    const float scale = which ? 1.0f : 0.18033688011112042f;  // Q: 0.125*log2(e)
    // stage Ct[s 128][n 256] stride 264
#pragma unroll
    for (int mt = 0; mt < 4; ++mt)
#pragma unroll
      for (int jn = 0; jn < 4; ++jn) {
        ushort4v t4;
#pragma unroll
        for (int r = 0; r < 4; ++r) t4[r] = f2bf(acc[mt][jn][r] * scale);
        const int row = (wave >> 2) * 64 + mt * 16 + l15;
        const int col = (wave & 3) * 64 + (jn >> 1) * 32 + (jn & 1) * 16 + quad * 4;
        *(ushort4v*)&smem[row * 264 + col] = t4;
      }
    __syncthreads();
#pragma unroll
    for (int t8 = 0; t8 < 8; ++t8) {
      const int c = t8 * 512 + tid;
      const int sr = c >> 5, ch = c & 31;
      const int hs = ch >> 3, hd8 = (ch & 7) * 8;
      const ushort8v val = *(const ushort8v*)&smem[sr * 264 + hs * 64 + hd8];
      *(ushort8v*)&dst[((size_t)((b * NHEAD + h0 + hs) * S_LEN + sl + sr)) * HDIM + hd8] = val;
    }
  } else {
    // V: stage TRANSPOSED Ct[n 256][s 128] stride 136, store Vt[b,h,hd,s]
#pragma unroll
    for (int mt = 0; mt < 4; ++mt)
#pragma unroll
      for (int jn = 0; jn < 4; ++jn) {
        ushort4v t4;
#pragma unroll
        for (int r = 0; r < 4; ++r) t4[r] = f2bf(acc[mt][jn][r]);
        const int nl = (wave & 3) * 64 + (jn >> 1) * 32 + (jn & 1) * 16 + l15;
        const int sc = (wave >> 2) * 64 + mt * 16 + quad * 4;
        *(ushort4v*)&smem[nl * 136 + sc] = t4;
      }
    __syncthreads();
#pragma unroll
    for (int t8 = 0; t8 < 8; ++t8) {
      const int c = t8 * 512 + tid;
      const int nl = c >> 4, sc8 = (c & 15) * 8;
      const ushort8v val = *(const ushort8v*)&smem[nl * 136 + sc8];
      *(ushort8v*)&Vto[((size_t)((b * NHEAD + h0 + (nl >> 6)) * HDIM + (nl & 63))) * S_LEN + sl + sc8] = val;
    }
  }
}

// ---------------------------------------------------------------------------
// Kernel 3: causal flash attention, S^T formulation, ASYNC-PIPELINED.
// R18: PAIRED q-tiles — each block processes qt=15-yy THEN qt=yy, so every
// block does exactly (2(15-yy)+2)+(2yy+2) = 34 key-tiles. Grid 64x8 = 512
// UNIFORM blocks = exactly 2/CU resident (capacity 3/CU) -> one clean round,
// zero tail. R16 counters showed the imbalance cost: Occ 40% of 75% cap,
// 32% dual-pipe idle (block work varied 16:1). Bonus: pass 2 re-reads K/V
// tiles pass 1 just streamed (same bh) -> L2-warm. Inner flow per pass is
// byte-identical to the verified kernel; per-pass re-init of qf/O/l_part;
// __syncthreads() between passes (staging-buffer hygiene).
// ---------------------------------------------------------------------------
__global__ __launch_bounds__(512, 6) void attn_kernel(
    const unsigned short* __restrict__ Qg_,
    const unsigned short* __restrict__ Kg_,
    const unsigned short* __restrict__ Vtg_,
    unsigned short* __restrict__ CTX)
{
  // shorts: buf0 K@0[4096] V@4096[4096] | buf1 K@8192 V@12288 | P@16384 8x[16*68]
  __shared__ unsigned short smem[25088];   // 50176 B
  const int tid  = threadIdx.x, wave = tid >> 6, lane = tid & 63;
  const int quad = lane >> 4, l15 = lane & 15;
  unsigned short* Pw = smem + 16384 + wave * 1088;   // [16][68] per wave

  const int bh = (int)blockIdx.x;
  const int yy = (int)blockIdx.y;                 // 0..7
  const size_t base = (size_t)bh * (S_LEN * HDIM);
  const unsigned short* Qg  = Qg_  + base;
  const unsigned short* Kg  = Kg_  + base;
  const unsigned short* Vtg = Vtg_ + base;        // [hd][s]

  const int strow = lane >> 3;
  const int stxc  = (lane & 7) ^ strow;
  const unsigned short* kstage = Kg  + (size_t)(wave * 8 + strow) * HDIM  + stxc * 8;
  const unsigned short* vstage = Vtg + (size_t)(wave * 8 + strow) * S_LEN + stxc * 8;
  unsigned short* kd0 = smem + wave * 512;
  unsigned short* vd0 = smem + 4096 + wave * 512;

  const int sw0 = ((quad)     ^ (l15 & 7)) * 8;   // K/V frag swizzled col offs
  const int sw1 = ((4 + quad) ^ (l15 & 7)) * 8;
  const floatx4 fzero = {0.f, 0.f, 0.f, 0.f};
  const int b = bh >> 4, h = bh & 15;

  for (int half = 0; half < 2; ++half) {
    const int qt = half ? yy : (15 - yy);         // long pass first
    const int q0 = qt * 128;
    const int qw = q0 + wave * 16;                // wave's 16 q-rows

    if (half) __syncthreads();                    // pass-1 readers done

    // prologue: async stage tile 0 -> buf 0
    async_cp16(kstage, kd0);
    async_cp16(vstage, vd0);

    // Q fragments direct from global (per pass; B-operand B[n=q][k=dim])
    bf16x8 qf[2];
#pragma unroll
    for (int ks = 0; ks < 2; ks++)
      qf[ks] = *(const bf16x8*)&Qg[(size_t)(qw + l15) * HDIM + ks * 32 + quad * 8];

    floatx4 O[4];
    float l_part = 0.f;
#pragma unroll
    for (int mt = 0; mt < 4; mt++) O[mt] = fzero;

    const int ntiles = 2 * qt + 2;   // covers keys 0..q0+127 >= qw+15

    for (int j = 0; j < ntiles; j++) {
      asm volatile("s_waitcnt vmcnt(0) lgkmcnt(0)\n\ts_barrier" ::: "memory");
      if (j + 1 < ntiles) {
        const int nb = (j + 1) & 1;
        async_cp16(kstage + (size_t)(j + 1) * 64 * HDIM, kd0 + nb * 8192);
        async_cp16(vstage + (size_t)(j + 1) * 64,        vd0 + nb * 8192);
      }
      const int k0 = j * 64;
      if (k0 > qw + 15) continue;                 // above diagonal for this wave
      const unsigned short* Ksb = smem + (j & 1) * 8192;
      const unsigned short* Vsb = Ksb + 4096;
      const int krel = qw + 15 - k0;              // max key offset needed

      // S^T = K Q^T  (A = K frag just-in-time, B = Q reg frag)
      floatx4 sa[4];
#pragma unroll
      for (int kt = 0; kt < 4; kt++) sa[kt] = fzero;
      __builtin_amdgcn_s_setprio(1);              // T5: favor MFMA wave (m191)
#pragma unroll
      for (int kt = 0; kt < 4; kt++) {
        if (kt * 16 <= krel) {
          const unsigned short* kr = &Ksb[(kt * 16 + l15) * 64];
          sa[kt] = __builtin_amdgcn_mfma_f32_16x16x32_bf16(*(const bf16x8*)(kr + sw0), qf[0], sa[kt], 0, 0, 0);
          sa[kt] = __builtin_amdgcn_mfma_f32_16x16x32_bf16(*(const bf16x8*)(kr + sw1), qf[1], sa[kt], 0, 0, 0);
        }
      }
      __builtin_amdgcn_s_setprio(0);

      const int qrow = qw + l15;                  // this lane's q (S^T col)
#pragma unroll
      for (int kt = 0; kt < 4; kt++) {
        const int kbase = k0 + kt * 16;
        unsigned short* pdst = &Pw[l15 * 68 + kt * 16 + quad * 4];
        if (kt * 16 <= krel) {
          if (kbase + 15 > qw) {                  // boundary subtile: mask
#pragma unroll
            for (int r = 0; r < 4; r++)
              if (kbase + quad * 4 + r > qrow) sa[kt][r] = -INFINITY;
          }
          const float p0 = EXP2F(sa[kt][0]), p1 = EXP2F(sa[kt][1]);
          const float p2 = EXP2F(sa[kt][2]), p3 = EXP2F(sa[kt][3]);
          l_part += (p0 + p1) + (p2 + p3);
          uint2 pk; pk.x = pack2bf(p0, p1); pk.y = pack2bf(p2, p3);
          *(uint2*)pdst = pk;
        } else if ((kt >> 1) * 32 <= krel) {      // zero-fill rest of read half
          uint2 z; z.x = 0u; z.y = 0u;
          *(uint2*)pdst = z;
        }
      }
      asm volatile("s_waitcnt lgkmcnt(0)" ::: "memory");  // P writes (wave-local)

      // O^T += V^T P^T : A = Vt frag (swizzled LDS), B = P frag (b64 reads)
#pragma unroll
      for (int ks = 0; ks < 2; ks++) {
        if (ks * 32 > krel) break;
        const unsigned short* ps = &Pw[l15 * 68 + ks * 32 + quad * 8];
        union { ushort4v h[2]; bf16x8 v; } pu;
        pu.h[0] = *(const ushort4v*)ps;
        pu.h[1] = *(const ushort4v*)(ps + 4);
        __builtin_amdgcn_s_setprio(1);            // T5: favor MFMA wave (m191)
#pragma unroll
        for (int mt = 0; mt < 4; mt++) {
          const bf16x8 vf = *(const bf16x8*)(&Vsb[(mt * 16 + l15) * 64] + (ks ? sw1 : sw0));
          O[mt] = __builtin_amdgcn_mfma_f32_16x16x32_bf16(vf, pu.v, O[mt], 0, 0, 0);
        }
        __builtin_amdgcn_s_setprio(0);
      }
    }

    // l: reduce partial sums across the 4 quads (keys were split across quads)
#pragma unroll
    for (int d = 16; d < 64; d <<= 1)
      l_part += __shfl_xor(l_part, d, 64);

    // epilogue: O^T (hd=row, q=col) -> Pw [q][hd] stride 68 -> coalesced CTX
    {
      const float inv = 1.0f / l_part;
#pragma unroll
      for (int mt = 0; mt < 4; mt++)
#pragma unroll
        for (int a = 0; a < 2; a++) {
          const unsigned int pk =
              (unsigned int)f2bf(O[mt][2 * a] * inv) |
              ((unsigned int)f2bf(O[mt][2 * a + 1] * inv) << 16);
          *(unsigned int*)&Pw[l15 * 68 + mt * 16 + quad * 4 + 2 * a] = pk;
        }
    }
    asm volatile("s_waitcnt lgkmcnt(0)" ::: "memory");
#pragma unroll
    for (int it = 0; it < 2; it++) {
      const int g = it * 64 + lane;
      const int row = g >> 3, c8 = (g & 7) * 8;
      union { ushort4v h[2]; ushort8v v; } ou;
      ou.h[0] = *(const ushort4v*)&Pw[row * 68 + c8];
      ou.h[1] = *(const ushort4v*)&Pw[row * 68 + c8 + 4];
      const int s = qw + row;
      *(ushort8v*)&CTX[((size_t)(b * S_LEN + s)) * KD + h * HDIM + c8] = ou.v;
    }
  }
}

// ---------------------------------------------------------------------------
// Kernel 4: output projection on the VERIFIED kloop12 structure.
// ctx[8192,1024] x W_o[1024,1024]^T + b_o -> fp32.  BM=128 x BN=256 ->
// grid 64x4 = 256 blocks = EXACTLY 1.0 round at 1 block/CU (96 KiB LDS).
// ---------------------------------------------------------------------------
__global__ __launch_bounds__(512, 2) void gemm_out12(
    const unsigned short* __restrict__ A,
    const unsigned short* __restrict__ Bw,
    const float* __restrict__ bias,
    float* __restrict__ out)
{
  __shared__ unsigned short smem[49152];   // 96 KiB
  const int tid  = threadIdx.x;
  const int wave = tid >> 6, lane = tid & 63;
  const int quad = lane >> 4, l15 = lane & 15;

  // XCD swizzle (256 = 8 x 32, bijective); m-outer within XCD
  const int bid = (int)blockIdx.x;
  const int tau = (bid & 7) * 32 + (bid >> 3);
  const int m0 = (tau >> 2) * 128, n0 = (tau & 3) * 256;

  const int strow = tid >> 3;                       // 0..63
  const int stxc  = (tid & 7) ^ (strow & 7);        // XOR-swizzled source chunk
  const unsigned short* gAs = A  + (size_t)(m0 + strow) * KD + stxc * 8;
  const unsigned short* gBs = Bw + (size_t)(n0 + strow) * KD + stxc * 8;

  const floatx4 fzero = {0.f, 0.f, 0.f, 0.f};
  floatx4 acc[4][4];
#pragma unroll
  for (int i = 0; i < 4; i++)
#pragma unroll
    for (int j = 0; j < 4; j++) acc[i][j] = fzero;

  kloop12<true>(gAs, gBs, smem, acc, wave, quad, l15);

  // SWAP n-major: acc[mt][jn][r] = C[m0+(w>>2)*64+mt*16+l15]
  //                                 [n0+(w&3)*64+(jn>>1)*32+(jn&1)*16+quad*4+r]
#pragma unroll
  for (int jn = 0; jn < 4; ++jn) {
    const int nb4 = n0 + (wave & 3) * 64 + (jn >> 1) * 32 + (jn & 1) * 16 + quad * 4;
    const float4v bb = *(const float4v*)&bias[nb4];
#pragma unroll
    for (int mt = 0; mt < 4; ++mt) {
      const int m = m0 + (wave >> 2) * 64 + mt * 16 + l15;
      float4v st;
#pragma unroll
      for (int r = 0; r < 4; ++r) st[r] = acc[mt][jn][r] + bb[r];
      *(float4v*)&out[(size_t)m * KD + nb4] = st;
    }
  }
}

// ---------------------------------------------------------------------------
extern "C" void kernel_launch(void* const* d_in, const int* in_sizes, int n_in,
                              void* d_out, int out_size, void* d_ws, size_t ws_size,
                              hipStream_t stream) {
  (void)in_sizes; (void)n_in; (void)out_size;
  const float* x  = (const float*)d_in[0];
  const float* wq = (const float*)d_in[1];
  const float* wk = (const float*)d_in[2];
  const float* wv = (const float*)d_in[3];
  const float* wo = (const float*)d_in[4];
  const float* bo = (const float*)d_in[5];
  float* out = (float*)d_out;

  if (ws_size < (size_t)92274688) return;
  char* ws = (char*)d_ws;
  unsigned short* xb    = (unsigned short*)(ws);
  unsigned short* wqkvb = (unsigned short*)(ws + (size_t)16777216);
  unsigned short* wob   = (unsigned short*)(ws + (size_t)23068672);
  unsigned short* qws   = (unsigned short*)(ws + (size_t)25165824);
  unsigned short* kws   = (unsigned short*)(ws + (size_t)41943040);
  unsigned short* vtws  = (unsigned short*)(ws + (size_t)58720256);
  unsigned short* ctxws = (unsigned short*)(ws + (size_t)75497472);

  cvt_kernel<<<12288, 256, 0, stream>>>(x, wq, wk, wv, wo, xb, wqkvb, wob);
  gemm_qkv12<<<768, 512, 0, stream>>>(xb, wqkvb, qws, kws, vtws);
  attn_kernel<<<dim3(64, 8), 512, 0, stream>>>(qws, kws, vtws, ctxws);
  gemm_out12<<<256, 512, 0, stream>>>(ctxws, wob, bo, out);
}

// Round 18
// 225.342 us; speedup vs baseline: 1.0439x; 1.0439x over previous
//
#include <hip/hip_runtime.h>
#include <cstdint>
#include <cstddef>

// Problem constants
#define S_LEN  2048
#define NHEAD  16
#define HDIM   64
#define KD     1024   // D_IN == D_OUT
#define BSROWS 8192   // B * S

typedef __attribute__((ext_vector_type(4))) float          floatx4;
typedef __attribute__((ext_vector_type(8))) __bf16         bf16x8;
typedef __attribute__((ext_vector_type(8))) unsigned short ushort8v;
typedef __attribute__((ext_vector_type(4))) unsigned short ushort4v;
typedef __attribute__((ext_vector_type(4))) float          float4v;

// fp32 -> bf16 round-to-nearest-even on the bit pattern (inputs are finite)
__device__ __forceinline__ unsigned short f2bf(float f) {
  unsigned int u = __float_as_uint(f);
  u += 0x7fffu + ((u >> 16) & 1u);
  return (unsigned short)(u >> 16);
}

// fast exp2 (single v_exp_f32)
#if __has_builtin(__builtin_amdgcn_exp2f)
#define EXP2F(x) __builtin_amdgcn_exp2f(x)
#else
#define EXP2F(x) exp2f(x)
#endif

// pack two fp32 into packed bf16 (truncation; bias cancels in O/l)
__device__ __forceinline__ unsigned int pack2bf(float a, float b) {
#if __has_builtin(__builtin_amdgcn_perm)
  return __builtin_amdgcn_perm(__float_as_uint(b), __float_as_uint(a), 0x07060302);
#else
  return (__float_as_uint(a) >> 16) | (__float_as_uint(b) & 0xffff0000u);
#endif
}

// async global->LDS, 16B per lane; LDS dest is wave-uniform base + lane*16
__device__ __forceinline__ void async_cp16(const void* gsrc, void* ldst) {
  __builtin_amdgcn_global_load_lds(
      (__attribute__((address_space(1))) void*)gsrc,
      (__attribute__((address_space(3))) void*)ldst,
      16, 0, 0);
}

// ---------------------------------------------------------------------------
// Kernel 1: fp32 -> bf16 conversion of x, W_q|W_k|W_v (concat), W_o
// ---------------------------------------------------------------------------
#define XN4 2097152   // B*S*D_IN / 4
#define WN4 262144    // 1024*1024 / 4

__global__ __launch_bounds__(256) void cvt_kernel(
    const float* __restrict__ x,  const float* __restrict__ wq,
    const float* __restrict__ wk, const float* __restrict__ wv,
    const float* __restrict__ wo,
    unsigned short* __restrict__ xb, unsigned short* __restrict__ wqkvb,
    unsigned short* __restrict__ wob)
{
  const int i = blockIdx.x * 256 + threadIdx.x;
  const float* src; unsigned short* dst; int off;
  if (i < XN4) { src = x; dst = xb; off = i; }
  else {
    const int j = i - XN4;
    if (j < WN4)          { src = wq; dst = wqkvb;           off = j; }
    else if (j < 2*WN4)   { src = wk; dst = wqkvb + 4*WN4;   off = j - WN4; }
    else if (j < 3*WN4)   { src = wv; dst = wqkvb + 8*WN4;   off = j - 2*WN4; }
    else                  { src = wo; dst = wob;             off = j - 3*WN4; }
  }
  const float4v v = ((const float4v*)src)[off];
  ushort4v o;
  o.x = f2bf(v.x); o.y = f2bf(v.y); o.z = f2bf(v.z); o.w = f2bf(v.w);
  ((ushort4v*)dst)[off] = o;
}

// ---------------------------------------------------------------------------
// R19: 128x128 counted-vmcnt QKV GEMM — 2 blocks/CU occupancy fix.
// R13/R17 counters: gemm_qkv12 at 96 KiB LDS = 1 block/CU (Occ 18%,
// MfmaUtil 28%) — barrier drains have no co-resident block to hide under.
// This variant: LDS = 2 buf x (A[128][64] + B[128][64]) = 64 KiB ->
// 2 blocks/CU; grid 64x24 = 1536 blocks = EXACTLY 3.0 rounds at 2/CU.
// Mechanics are a strict subset of the HW-verified kloop12: single phase
// per K-tile (16 MFMA/wave), stage A+B halves (4 cp16) at tile top,
// ONE vmcnt(4) per tile (outstanding after stage = 4+4, wait leaves the
// 4 just-issued -> tile t fully resident; t=15 vmcnt(0)); dbuf -> no WAR;
// same XOR source swizzle + linear LDS dest + sw0/sw1 reads; setprio.
// 8 waves = 2 row-bands(64) x 4 col-bands(32); acc[4][2] frags.
// ---------------------------------------------------------------------------
__device__ __forceinline__ void stage_h128(
    const int h, const int tk,
    const unsigned short* __restrict__ gAs,
    const unsigned short* __restrict__ gBs,
    unsigned short* smem, const int wave)
{
  const int bufo = (tk & 1) * 16384;
  const unsigned short* g = (h == 0) ? (gAs + tk * 64) : (gBs + tk * 64);
  unsigned short* l = smem + bufo + h * 8192 + wave * 512;
  async_cp16(g,                   l);
  async_cp16(g + (size_t)64 * KD, l + 4096);
}

template<bool SWAP>
__device__ __forceinline__ void kloop128n(
    const unsigned short* __restrict__ gAs,
    const unsigned short* __restrict__ gBs,
    unsigned short* smem, floatx4 (&acc)[4][2],
    const int wave, const int quad, const int l15)
{
  const int ar_base = (wave >> 2) * 64 + l15;   // 2 row-bands x 64
  const int bc_base = (wave & 3) * 32 + l15;    // 4 col-bands x 32
  const int sw0 = ((quad)     ^ (l15 & 7)) * 8; // chunk swizzle, ks=0
  const int sw1 = ((4 + quad) ^ (l15 & 7)) * 8; // chunk swizzle, ks=1

  bf16x8 af[4][2];     // A frags
  bf16x8 bfr[2][2];    // B frags

  // prologue: both halves of tile 0
  stage_h128(0, 0, gAs, gBs, smem, wave);
  stage_h128(1, 0, gAs, gBs, smem, wave);

#pragma unroll 2
  for (int t = 0; t < 16; ++t) {
    const unsigned short* As = smem + (t & 1) * 16384;
    const unsigned short* Bs = As + 8192;

    asm volatile("s_barrier" ::: "memory");       // close prev tile
    if (t + 1 < 16) {
      stage_h128(0, t + 1, gAs, gBs, smem, wave); // A(t+1)
      stage_h128(1, t + 1, gAs, gBs, smem, wave); // B(t+1)
    }
    if (t < 15) asm volatile("s_waitcnt vmcnt(4)\n\ts_barrier" ::: "memory");
    else        asm volatile("s_waitcnt vmcnt(0)\n\ts_barrier" ::: "memory");
#pragma unroll
    for (int mt = 0; mt < 4; ++mt) {
      const unsigned short* ar = &As[(ar_base + mt * 16) * 64];
      af[mt][0] = *(const bf16x8*)(ar + sw0);
      af[mt][1] = *(const bf16x8*)(ar + sw1);
    }
#pragma unroll
    for (int nt = 0; nt < 2; ++nt) {
      const unsigned short* br = &Bs[(bc_base + nt * 16) * 64];
      bfr[nt][0] = *(const bf16x8*)(br + sw0);
      bfr[nt][1] = *(const bf16x8*)(br + sw1);
    }
    __builtin_amdgcn_s_setprio(1);
#pragma unroll
    for (int mt = 0; mt < 4; ++mt)
#pragma unroll
      for (int nt = 0; nt < 2; ++nt)
#pragma unroll
        for (int ks = 0; ks < 2; ++ks) {
          if (SWAP)
            acc[mt][nt] = __builtin_amdgcn_mfma_f32_16x16x32_bf16(
                bfr[nt][ks], af[mt][ks], acc[mt][nt], 0, 0, 0);
          else
            acc[mt][nt] = __builtin_amdgcn_mfma_f32_16x16x32_bf16(
                af[mt][ks], bfr[nt][ks], acc[mt][nt], 0, 0, 0);
        }
    __builtin_amdgcn_s_setprio(0);
  }
}

// fragment coords (SWAP, n-major):  m = (w>>2)*64+mt*16+l15,
//                                   n = (w&3)*32+nt*16+quad*4+r
// (no-SWAP, m-major): m gets quad*4+r, n gets l15.
__global__ __launch_bounds__(512, 4) void gemm_qkv128(
    const unsigned short* __restrict__ A,
    const unsigned short* __restrict__ Bw,
    unsigned short* __restrict__ Qo,
    unsigned short* __restrict__ Ko,
    unsigned short* __restrict__ Vto)
{
  __shared__ unsigned short smem[32768];   // 64 KiB (epilogue reuses 128x136)
  const int tid  = threadIdx.x;
  const int wave = tid >> 6, lane = tid & 63;
  const int quad = lane >> 4, l15 = lane & 15;

  // XCD swizzle (1536 = 8 x 192, bijective); m-outer within XCD: 8 A-panels
  // (2 MB) L2-resident per XCD.
  const int bid = (int)blockIdx.x;
  const int tau = (bid & 7) * 192 + (bid >> 3);
  const int m0 = (tau / 24) * 128, n0 = (tau % 24) * 128;

  const int strow = tid >> 3;                       // 0..63
  const int stxc  = (tid & 7) ^ (strow & 7);        // XOR-swizzled source chunk
  const unsigned short* gAs = A  + (size_t)(m0 + strow) * KD + stxc * 8;
  const unsigned short* gBs = Bw + (size_t)(n0 + strow) * KD + stxc * 8;

  const floatx4 fzero = {0.f, 0.f, 0.f, 0.f};
  floatx4 acc[4][2];
#pragma unroll
  for (int i = 0; i < 4; i++)
#pragma unroll
    for (int j = 0; j < 2; j++) acc[i][j] = fzero;

  const int which = n0 >> 10;                       // 0:Q 1:K 2:V
  if (which < 2) kloop128n<true >(gAs, gBs, smem, acc, wave, quad, l15);
  else           kloop128n<false>(gAs, gBs, smem, acc, wave, quad, l15);

  const int h0 = (n0 & 1023) >> 6;                  // first of 2 heads
  const int b = m0 >> 11, sl = m0 & 2047;
  __syncthreads();                                  // staging dead -> reuse LDS

  if (which < 2) {
    unsigned short* dst = which ? Ko : Qo;
    const float scale = which ? 1.0f : 0.18033688011112042f;  // Q: 0.125*log2(e)
    // stage Ct[s 128][n 128] stride 136
#pragma unroll
    for (int mt = 0; mt < 4; ++mt)
#pragma unroll
      for (int nt = 0; nt < 2; ++nt) {
        ushort4v t4;
#pragma unroll
        for (int r = 0; r < 4; ++r) t4[r] = f2bf(acc[mt][nt][r] * scale);
        const int row = (wave >> 2) * 64 + mt * 16 + l15;
        const int col = (wave & 3) * 32 + nt * 16 + quad * 4;
        *(ushort4v*)&smem[row * 136 + col] = t4;
      }
    __syncthreads();
#pragma unroll
    for (int t8 = 0; t8 < 4; ++t8) {
      const int c = t8 * 512 + tid;                 // 128 rows x 16 chunks
      const int sr = c >> 4, ch = c & 15;
      const int hs = ch >> 3, hd8 = (ch & 7) * 8;
      const ushort8v val = *(const ushort8v*)&smem[sr * 136 + hs * 64 + hd8];
      *(ushort8v*)&dst[((size_t)((b * NHEAD + h0 + hs) * S_LEN + sl + sr)) * HDIM + hd8] = val;
    }
  } else {
    // V (m-major acc): stage TRANSPOSED Ct[n 128][s 128] stride 136
#pragma unroll
    for (int mt = 0; mt < 4; ++mt)
#pragma unroll
      for (int nt = 0; nt < 2; ++nt) {
        ushort4v t4;
#pragma unroll
        for (int r = 0; r < 4; ++r) t4[r] = f2bf(acc[mt][nt][r]);
        const int nl = (wave & 3) * 32 + nt * 16 + l15;
        const int sc = (wave >> 2) * 64 + mt * 16 + quad * 4;
        *(ushort4v*)&smem[nl * 136 + sc] = t4;
      }
    __syncthreads();
#pragma unroll
    for (int t8 = 0; t8 < 4; ++t8) {
      const int c = t8 * 512 + tid;                 // 128 nl x 16 s-chunks
      const int nl = c >> 4, sc8 = (c & 15) * 8;
      const ushort8v val = *(const ushort8v*)&smem[nl * 136 + sc8];
      *(ushort8v*)&Vto[((size_t)((b * NHEAD + h0 + (nl >> 6)) * HDIM + (nl & 63))) * S_LEN + sl + sc8] = val;
    }
  }
}

// ---------------------------------------------------------------------------
// R15 kloop12 (HW-VERIFIED) — still used by gemm_out12.
// ---------------------------------------------------------------------------
__device__ __forceinline__ void stage_h12(
    const int h, const int tk,
    const unsigned short* __restrict__ gAs,
    const unsigned short* __restrict__ gBs,
    unsigned short* smem, const int wave)
{
  const int bufo = (tk & 1) * 24576;
  const unsigned short* g;
  unsigned short* l;
  if (h == 0)      { g = gAs + tk * 64;                      l = smem + bufo + wave * 512; }
  else if (h == 1) { g = gBs + tk * 64;                      l = smem + bufo + 8192  + wave * 512; }
  else             { g = gBs + (size_t)128 * KD + tk * 64;   l = smem + bufo + 16384 + wave * 512; }
  async_cp16(g,                   l);
  async_cp16(g + (size_t)64 * KD, l + 4096);
}

template<bool SWAP>
__device__ __forceinline__ void kloop12(
    const unsigned short* __restrict__ gAs,
    const unsigned short* __restrict__ gBs,
    unsigned short* smem, floatx4 (&acc)[4][4],
    const int wave, const int quad, const int l15)
{
  const int ar_base = (wave >> 2) * 64 + l15;
  const int bc_base = (wave & 3) * 64 + l15;
  const int sw0 = ((quad)     ^ (l15 & 7)) * 8;
  const int sw1 = ((4 + quad) ^ (l15 & 7)) * 8;

  bf16x8 af[4][2];
  bf16x8 bfr[2][2];

  stage_h12(0, 0, gAs, gBs, smem, wave);
  stage_h12(1, 0, gAs, gBs, smem, wave);
  stage_h12(2, 0, gAs, gBs, smem, wave);

#define MFMAQ12(nh)                                                            \
  __builtin_amdgcn_s_setprio(1);                                               \
  _Pragma("unroll") for (int mt = 0; mt < 4; ++mt)                             \
    _Pragma("unroll") for (int nt = 0; nt < 2; ++nt)                           \
      _Pragma("unroll") for (int ks = 0; ks < 2; ++ks) {                       \
        if (SWAP)                                                              \
          acc[mt][(nh)*2+nt] = __builtin_amdgcn_mfma_f32_16x16x32_bf16(        \
              bfr[nt][ks], af[mt][ks], acc[mt][(nh)*2+nt], 0, 0, 0);           \
        else                                                                   \
          acc[mt][(nh)*2+nt] = __builtin_amdgcn_mfma_f32_16x16x32_bf16(        \
              af[mt][ks], bfr[nt][ks], acc[mt][(nh)*2+nt], 0, 0, 0);           \
      }                                                                        \
  __builtin_amdgcn_s_setprio(0);

#pragma unroll 2
  for (int t = 0; t < 16; ++t) {
    const unsigned short* As = smem + (t & 1) * 24576;
    const unsigned short* Bs = As + 8192;

    asm volatile("s_barrier" ::: "memory");
    if (t + 1 < 16) {
      stage_h12(0, t + 1, gAs, gBs, smem, wave);
      stage_h12(1, t + 1, gAs, gBs, smem, wave);
    }
    if (t < 15) asm volatile("s_waitcnt vmcnt(4)\n\ts_barrier" ::: "memory");
    else        asm volatile("s_waitcnt vmcnt(0)\n\ts_barrier" ::: "memory");
#pragma unroll
    for (int mt = 0; mt < 4; ++mt) {
      const unsigned short* ar = &As[(ar_base + mt * 16) * 64];
      af[mt][0] = *(const bf16x8*)(ar + sw0);
      af[mt][1] = *(const bf16x8*)(ar + sw1);
    }
#pragma unroll
    for (int nt = 0; nt < 2; ++nt) {
      const unsigned short* br = &Bs[(bc_base + nt * 16) * 64];
      bfr[nt][0] = *(const bf16x8*)(br + sw0);
      bfr[nt][1] = *(const bf16x8*)(br + sw1);
    }
    MFMAQ12(0)

    asm volatile("s_barrier" ::: "memory");
    if (t + 1 < 16) stage_h12(2, t + 1, gAs, gBs, smem, wave);
#pragma unroll
    for (int nt = 0; nt < 2; ++nt) {
      const unsigned short* br = &Bs[(bc_base + 32 + nt * 16) * 64];
      bfr[nt][0] = *(const bf16x8*)(br + sw0);
      bfr[nt][1] = *(const bf16x8*)(br + sw1);
    }
    MFMAQ12(1)
  }
#undef MFMAQ12
}

// ---------------------------------------------------------------------------
// Kernel 3: causal flash attention — R16 verbatim (best measured attn:
// 62.6 µs). R18's paired-qt experiment was neutral-negative (63.5 µs):
// chip throughput ~275 tile-units/µs under BOTH schedules -> attn is
// pipe/latency-bound per CU, not schedule-bound.
// ---------------------------------------------------------------------------
__global__ __launch_bounds__(512, 6) void attn_kernel(
    const unsigned short* __restrict__ Qg_,
    const unsigned short* __restrict__ Kg_,
    const unsigned short* __restrict__ Vtg_,
    unsigned short* __restrict__ CTX)
{
  // shorts: buf0 K@0[4096] V@4096[4096] | buf1 K@8192 V@12288 | P@16384 8x[16*68]
  __shared__ unsigned short smem[25088];   // 50176 B
  const int tid  = threadIdx.x, wave = tid >> 6, lane = tid & 63;
  const int quad = lane >> 4, l15 = lane & 15;
  unsigned short* Pw = smem + 16384 + wave * 1088;   // [16][68] per wave

  const int bh = (int)blockIdx.x;
  const int yy = (int)blockIdx.y;
  // qt perm: {0,1,2,3, 7,6,5,4, 8,9,10,11, 15,14,13,12} — columns sum to 30
  const int qt = (yy < 4) ? yy : (yy < 8) ? (11 - yy) : (yy < 12) ? yy : (27 - yy);
  const int q0 = qt * 128;
  const size_t base = (size_t)bh * (S_LEN * HDIM);
  const unsigned short* Qg  = Qg_  + base;
  const unsigned short* Kg  = Kg_  + base;
  const unsigned short* Vtg = Vtg_ + base;        // [hd][s]
  const int qw = q0 + wave * 16;                  // wave's 16 q-rows

  const int strow = lane >> 3;
  const int stxc  = (lane & 7) ^ strow;
  const unsigned short* kstage = Kg  + (size_t)(wave * 8 + strow) * HDIM  + stxc * 8;
  const unsigned short* vstage = Vtg + (size_t)(wave * 8 + strow) * S_LEN + stxc * 8;
  unsigned short* kd0 = smem + wave * 512;
  unsigned short* vd0 = smem + 4096 + wave * 512;

  // prologue: async stage tile 0 -> buf 0
  async_cp16(kstage, kd0);
  async_cp16(vstage, vd0);

  // Q fragments direct from global (one-time; B-operand B[n=q][k=dim])
  bf16x8 qf[2];
#pragma unroll
  for (int ks = 0; ks < 2; ks++)
    qf[ks] = *(const bf16x8*)&Qg[(size_t)(qw + l15) * HDIM + ks * 32 + quad * 8];

  const int sw0 = ((quad)     ^ (l15 & 7)) * 8;   // K/V frag swizzled col offs
  const int sw1 = ((4 + quad) ^ (l15 & 7)) * 8;

  const floatx4 fzero = {0.f, 0.f, 0.f, 0.f};
  floatx4 O[4];
  float l_part = 0.f;
#pragma unroll
  for (int mt = 0; mt < 4; mt++) O[mt] = fzero;

  const int ntiles = 2 * qt + 2;   // covers keys 0..q0+127 >= qw+15

  for (int j = 0; j < ntiles; j++) {
    asm volatile("s_waitcnt vmcnt(0) lgkmcnt(0)\n\ts_barrier" ::: "memory");
    if (j + 1 < ntiles) {
      const int nb = (j + 1) & 1;
      async_cp16(kstage + (size_t)(j + 1) * 64 * HDIM, kd0 + nb * 8192);
      async_cp16(vstage + (size_t)(j + 1) * 64,        vd0 + nb * 8192);
    }
    const int k0 = j * 64;
    if (k0 > qw + 15) continue;                 // above diagonal for this wave
    const unsigned short* Ksb = smem + (j & 1) * 8192;
    const unsigned short* Vsb = Ksb + 4096;
    const int krel = qw + 15 - k0;              // max key offset needed

    // S^T = K Q^T  (A = K frag just-in-time, B = Q reg frag)
    floatx4 sa[4];
#pragma unroll
    for (int kt = 0; kt < 4; kt++) sa[kt] = fzero;
    __builtin_amdgcn_s_setprio(1);              // T5: favor MFMA wave (m191)
#pragma unroll
    for (int kt = 0; kt < 4; kt++) {
      if (kt * 16 <= krel) {
        const unsigned short* kr = &Ksb[(kt * 16 + l15) * 64];
        sa[kt] = __builtin_amdgcn_mfma_f32_16x16x32_bf16(*(const bf16x8*)(kr + sw0), qf[0], sa[kt], 0, 0, 0);
        sa[kt] = __builtin_amdgcn_mfma_f32_16x16x32_bf16(*(const bf16x8*)(kr + sw1), qf[1], sa[kt], 0, 0, 0);
      }
    }
    __builtin_amdgcn_s_setprio(0);

    const int qrow = qw + l15;                  // this lane's q (S^T col)
#pragma unroll
    for (int kt = 0; kt < 4; kt++) {
      const int kbase = k0 + kt * 16;
      unsigned short* pdst = &Pw[l15 * 68 + kt * 16 + quad * 4];
      if (kt * 16 <= krel) {
        if (kbase + 15 > qw) {                  // boundary subtile: mask
#pragma unroll
          for (int r = 0; r < 4; r++)
            if (kbase + quad * 4 + r > qrow) sa[kt][r] = -INFINITY;
        }
        const float p0 = EXP2F(sa[kt][0]), p1 = EXP2F(sa[kt][1]);
        const float p2 = EXP2F(sa[kt][2]), p3 = EXP2F(sa[kt][3]);
        l_part += (p0 + p1) + (p2 + p3);
        uint2 pk; pk.x = pack2bf(p0, p1); pk.y = pack2bf(p2, p3);
        *(uint2*)pdst = pk;
      } else if ((kt >> 1) * 32 <= krel) {      // zero-fill rest of read half
        uint2 z; z.x = 0u; z.y = 0u;
        *(uint2*)pdst = z;
      }
    }
    asm volatile("s_waitcnt lgkmcnt(0)" ::: "memory");  // P writes (wave-local)

    // O^T += V^T P^T : A = Vt frag (swizzled LDS), B = P frag (b64 reads)
#pragma unroll
    for (int ks = 0; ks < 2; ks++) {
      if (ks * 32 > krel) break;
      const unsigned short* ps = &Pw[l15 * 68 + ks * 32 + quad * 8];
      union { ushort4v h[2]; bf16x8 v; } pu;
      pu.h[0] = *(const ushort4v*)ps;
      pu.h[1] = *(const ushort4v*)(ps + 4);
      __builtin_amdgcn_s_setprio(1);            // T5: favor MFMA wave (m191)
#pragma unroll
      for (int mt = 0; mt < 4; mt++) {
        const bf16x8 vf = *(const bf16x8*)(&Vsb[(mt * 16 + l15) * 64] + (ks ? sw1 : sw0));
        O[mt] = __builtin_amdgcn_mfma_f32_16x16x32_bf16(vf, pu.v, O[mt], 0, 0, 0);
      }
      __builtin_amdgcn_s_setprio(0);
    }
  }

  // l: reduce partial sums across the 4 quads (keys were split across quads)
#pragma unroll
  for (int d = 16; d < 64; d <<= 1)
    l_part += __shfl_xor(l_part, d, 64);

  // epilogue: O^T (hd=row, q=col) -> Pw [q][hd] stride 68 -> coalesced CTX
  {
    const float inv = 1.0f / l_part;
#pragma unroll
    for (int mt = 0; mt < 4; mt++)
#pragma unroll
      for (int a = 0; a < 2; a++) {
        const unsigned int pk =
            (unsigned int)f2bf(O[mt][2 * a] * inv) |
            ((unsigned int)f2bf(O[mt][2 * a + 1] * inv) << 16);
        *(unsigned int*)&Pw[l15 * 68 + mt * 16 + quad * 4 + 2 * a] = pk;
      }
  }
  asm volatile("s_waitcnt lgkmcnt(0)" ::: "memory");
  const int b = bh >> 4, h = bh & 15;
#pragma unroll
  for (int it = 0; it < 2; it++) {
    const int g = it * 64 + lane;
    const int row = g >> 3, c8 = (g & 7) * 8;
    union { ushort4v h[2]; ushort8v v; } ou;
    ou.h[0] = *(const ushort4v*)&Pw[row * 68 + c8];
    ou.h[1] = *(const ushort4v*)&Pw[row * 68 + c8 + 4];
    const int s = qw + row;
    *(ushort8v*)&CTX[((size_t)(b * S_LEN + s)) * KD + h * HDIM + c8] = ou.v;
  }
}

// ---------------------------------------------------------------------------
// Kernel 4: output projection on the VERIFIED kloop12 structure (unchanged).
// ---------------------------------------------------------------------------
__global__ __launch_bounds__(512, 2) void gemm_out12(
    const unsigned short* __restrict__ A,
    const unsigned short* __restrict__ Bw,
    const float* __restrict__ bias,
    float* __restrict__ out)
{
  __shared__ unsigned short smem[49152];   // 96 KiB
  const int tid  = threadIdx.x;
  const int wave = tid >> 6, lane = tid & 63;
  const int quad = lane >> 4, l15 = lane & 15;

  const int bid = (int)blockIdx.x;
  const int tau = (bid & 7) * 32 + (bid >> 3);
  const int m0 = (tau >> 2) * 128, n0 = (tau & 3) * 256;

  const int strow = tid >> 3;
  const int stxc  = (tid & 7) ^ (strow & 7);
  const unsigned short* gAs = A  + (size_t)(m0 + strow) * KD + stxc * 8;
  const unsigned short* gBs = Bw + (size_t)(n0 + strow) * KD + stxc * 8;

  const floatx4 fzero = {0.f, 0.f, 0.f, 0.f};
  floatx4 acc[4][4];
#pragma unroll
  for (int i = 0; i < 4; i++)
#pragma unroll
    for (int j = 0; j < 4; j++) acc[i][j] = fzero;

  kloop12<true>(gAs, gBs, smem, acc, wave, quad, l15);

#pragma unroll
  for (int jn = 0; jn < 4; ++jn) {
    const int nb4 = n0 + (wave & 3) * 64 + (jn >> 1) * 32 + (jn & 1) * 16 + quad * 4;
    const float4v bb = *(const float4v*)&bias[nb4];
#pragma unroll
    for (int mt = 0; mt < 4; ++mt) {
      const int m = m0 + (wave >> 2) * 64 + mt * 16 + l15;
      float4v st;
#pragma unroll
      for (int r = 0; r < 4; ++r) st[r] = acc[mt][jn][r] + bb[r];
      *(float4v*)&out[(size_t)m * KD + nb4] = st;
    }
  }
}

// ---------------------------------------------------------------------------
extern "C" void kernel_launch(void* const* d_in, const int* in_sizes, int n_in,
                              void* d_out, int out_size, void* d_ws, size_t ws_size,
                              hipStream_t stream) {
  (void)in_sizes; (void)n_in; (void)out_size;
  const float* x  = (const float*)d_in[0];
  const float* wq = (const float*)d_in[1];
  const float* wk = (const float*)d_in[2];
  const float* wv = (const float*)d_in[3];
  const float* wo = (const float*)d_in[4];
  const float* bo = (const float*)d_in[5];
  float* out = (float*)d_out;

  if (ws_size < (size_t)92274688) return;
  char* ws = (char*)d_ws;
  unsigned short* xb    = (unsigned short*)(ws);
  unsigned short* wqkvb = (unsigned short*)(ws + (size_t)16777216);
  unsigned short* wob   = (unsigned short*)(ws + (size_t)23068672);
  unsigned short* qws   = (unsigned short*)(ws + (size_t)25165824);
  unsigned short* kws   = (unsigned short*)(ws + (size_t)41943040);
  unsigned short* vtws  = (unsigned short*)(ws + (size_t)58720256);
  unsigned short* ctxws = (unsigned short*)(ws + (size_t)75497472);

  cvt_kernel<<<12288, 256, 0, stream>>>(x, wq, wk, wv, wo, xb, wqkvb, wob);
  gemm_qkv128<<<1536, 512, 0, stream>>>(xb, wqkvb, qws, kws, vtws);
  attn_kernel<<<dim3(64, 16), 512, 0, stream>>>(qws, kws, vtws, ctxws);
  gemm_out12<<<256, 512, 0, stream>>>(ctxws, wob, bo, out);
}